// Round 5
// baseline (245.104 us; speedup 1.0000x reference)
//
#include <hip/hip_runtime.h>
#include <stdint.h>

// Problem dims (fixed)
#define BB 2
#define SS 2048
#define DD 1024
#define NH 16
#define HD 64
#define MM 4096   // BB*SS

typedef __bf16 bf16x8 __attribute__((ext_vector_type(8)));
typedef __bf16 bf16x4 __attribute__((ext_vector_type(4)));
typedef float  f32x4  __attribute__((ext_vector_type(4)));

__device__ __forceinline__ unsigned short f2bf(float f) {
    __bf16 h = (__bf16)f;                       // hw v_cvt, RNE
    return __builtin_bit_cast(unsigned short, h);
}

// async global->LDS, 16B per lane. LDS dst must be wave-uniform base + lane*16.
__device__ __forceinline__ void async_cp16(const void* g, const void* l) {
    __builtin_amdgcn_global_load_lds(
        (const __attribute__((address_space(1))) void*)(uintptr_t)g,
        (__attribute__((address_space(3))) void*)(uint32_t)(uintptr_t)l,
        16, 0, 0);
}

__device__ __forceinline__ f32x4 mfma16(bf16x8 a, bf16x8 b, f32x4 c) {
    return __builtin_amdgcn_mfma_f32_16x16x32_bf16(a, b, c, 0, 0, 0);
}

// ---------------- fused prep: H->Hb+Vt (blocks 0..511) and W->bf16 (blocks 512..2047) ----
__global__ __launch_bounds__(256) void k_prep(const float* __restrict__ H,
                                              const float* __restrict__ Wq,
                                              const float* __restrict__ Wk,
                                              const float* __restrict__ Wo,
                                              unsigned short* __restrict__ Hb,
                                              unsigned short* __restrict__ Vt,
                                              unsigned short* __restrict__ Wqb,
                                              unsigned short* __restrict__ Wkb,
                                              unsigned short* __restrict__ Wob) {
    __shared__ float tile[128][68];
    const int bx = blockIdx.x;
    const int t = threadIdx.x;
    if (bx >= 512) {  // weight conversion
        int g = bx - 512;
        const float* src; unsigned short* dst; int base;
        if (g < 512)       { src = Wq; dst = Wqb; base = g; }
        else if (g < 1024) { src = Wk; dst = Wkb; base = g - 512; }
        else               { src = Wo; dst = Wob; base = g - 1024; }
        int i = (base * 256 + t) * 8;
        float4 a = *(const float4*)(src + i);
        float4 b = *(const float4*)(src + i + 4);
        unsigned short o[8];
        o[0] = f2bf(a.x); o[1] = f2bf(a.y); o[2] = f2bf(a.z); o[3] = f2bf(a.w);
        o[4] = f2bf(b.x); o[5] = f2bf(b.y); o[6] = f2bf(b.z); o[7] = f2bf(b.w);
        *(ulonglong2*)(dst + i) = *(ulonglong2*)o;
        return;
    }
    const int sb = bx & 15, h = (bx >> 4) & 15, b = bx >> 8;
    const int col4 = t & 15;
    const int srow0 = t >> 4;
#pragma unroll
    for (int p = 0; p < 8; ++p) {
        int s = p * 16 + srow0;
        float4 v = *(const float4*)(H + (size_t)(b * SS + sb * 128 + s) * DD + h * HD + col4 * 4);
        *(float4*)&tile[s][col4 * 4] = v;
    }
    __syncthreads();
#pragma unroll
    for (int it = 0; it < 4; ++it) {
        int task = it * 256 + t;
        int s = task >> 3;
        int dg = task & 7;
        unsigned short pk[8];
#pragma unroll
        for (int j = 0; j < 8; ++j) pk[j] = f2bf(tile[s][dg * 8 + j]);
        *(ulonglong2*)(Hb + (size_t)(b * SS + sb * 128 + s) * DD + h * HD + dg * 8) = *(ulonglong2*)pk;
    }
#pragma unroll
    for (int it = 0; it < 4; ++it) {
        int task = it * 256 + t;
        int d = task >> 4;
        int sg = task & 15;
        unsigned short pk[8];
#pragma unroll
        for (int j = 0; j < 8; ++j) pk[j] = f2bf(tile[sg * 8 + j][d]);
        *(ulonglong2*)(Vt + (size_t)((b * NH + h) * HD + d) * SS + sb * 128 + sg * 8) = *(ulonglong2*)pk;
    }
}

// ---------------- TM x 128 MFMA GEMM, BK=64, double-buffered, 1 barrier/iter ----------------
// C[m][n] = (sum_k A[m][k]*Bt[n][k] + bias[n]) * oscale.  A:[*,1024], Bt:[1024,1024] bf16.
template <int TM, bool BF16OUT>
__device__ __forceinline__ void gemm_body(const unsigned short* __restrict__ A,
                                          const unsigned short* __restrict__ Bt,
                                          const float* __restrict__ bias,
                                          void* __restrict__ Cp, float oscale) {
    constexpr int MT = TM / 32;            // m-frags per wave (waves are 2x2)
    constexpr int AR = TM / 32;            // A staging rounds: TM*8 chunks / 256 lanes
    __shared__ unsigned short lsA[2][TM * 64];
    __shared__ unsigned short lsB[2][128 * 64];
    const int tid = threadIdx.x;
    const int lane = tid & 63;
    const int w = tid >> 6;
    const int wm = w & 1, wn = w >> 1;
    const int r = lane & 15, quad = lane >> 4;
    const int mBase = blockIdx.y * TM;
    const int nBase = blockIdx.x * 128;

    // staging addresses (row-of-128B = 8 chunks of 16B); advance by 64 k per buffer
    const unsigned short* gA[AR]; uint laOff[AR];
#pragma unroll
    for (int t = 0; t < AR; ++t) {
        int l = t * 256 + tid;
        int c = l ^ ((l >> 3) & 7);
        int row = c >> 3, kc = c & 7;
        gA[t] = A + (size_t)(mBase + row) * 1024 + kc * 8;
        laOff[t] = l * 8;
    }
    const unsigned short* gB[4]; uint lbOff[4];
#pragma unroll
    for (int t = 0; t < 4; ++t) {
        int l = t * 256 + tid;
        int c = l ^ ((l >> 3) & 7);
        int row = c >> 3, kc = c & 7;
        gB[t] = Bt + (size_t)(nBase + row) * 1024 + kc * 8;
        lbOff[t] = l * 8;
    }
    // fragment read offsets, per k-half
    uint aOff[2][MT], bOff[2][4];
#pragma unroll
    for (int hh = 0; hh < 2; ++hh) {
#pragma unroll
        for (int mt = 0; mt < MT; ++mt) {
            int rowA = wm * (TM / 2) + mt * 16 + r;
            int c = rowA * 8 + hh * 4 + quad;
            aOff[hh][mt] = (uint)((c ^ ((c >> 3) & 7)) * 8);
        }
#pragma unroll
        for (int nt = 0; nt < 4; ++nt) {
            int rowB = wn * 64 + nt * 16 + r;
            int c = rowB * 8 + hh * 4 + quad;
            bOff[hh][nt] = (uint)((c ^ ((c >> 3) & 7)) * 8);
        }
    }

    f32x4 acc[MT][4];
#pragma unroll
    for (int i = 0; i < MT; ++i)
#pragma unroll
        for (int j = 0; j < 4; ++j) acc[i][j] = f32x4{0.f, 0.f, 0.f, 0.f};

    auto stage = [&](int buf) {
#pragma unroll
        for (int t = 0; t < AR; ++t) { async_cp16(gA[t], &lsA[buf][laOff[t]]); gA[t] += 64; }
#pragma unroll
        for (int t = 0; t < 4; ++t)  { async_cp16(gB[t], &lsB[buf][lbOff[t]]); gB[t] += 64; }
    };

    stage(0);
    for (int kb = 0; kb < 16; ++kb) {
        const int cur = kb & 1;
        __syncthreads();   // drains vmcnt: buf[cur] ready, prev reads of buf[cur^1] done
        if (kb + 1 < 16) stage(cur ^ 1);

#pragma unroll
        for (int hh = 0; hh < 2; ++hh) {
            bf16x8 af[MT], bf[4];
#pragma unroll
            for (int mt = 0; mt < MT; ++mt) af[mt] = *(const bf16x8*)&lsA[cur][aOff[hh][mt]];
#pragma unroll
            for (int nt = 0; nt < 4; ++nt)  bf[nt] = *(const bf16x8*)&lsB[cur][bOff[hh][nt]];
#pragma unroll
            for (int mt = 0; mt < MT; ++mt)
#pragma unroll
                for (int nt = 0; nt < 4; ++nt)
                    acc[mt][nt] = mfma16(af[mt], bf[nt], acc[mt][nt]);
        }
    }

    float bv[4];
#pragma unroll
    for (int nt = 0; nt < 4; ++nt) bv[nt] = bias[nBase + wn * 64 + nt * 16 + r];
#pragma unroll
    for (int mt = 0; mt < MT; ++mt)
#pragma unroll
        for (int nt = 0; nt < 4; ++nt) {
            int colg = nBase + wn * 64 + nt * 16 + r;
#pragma unroll
            for (int reg = 0; reg < 4; ++reg) {
                int rowg = mBase + wm * (TM / 2) + mt * 16 + quad * 4 + reg;
                float v = (acc[mt][nt][reg] + bv[nt]) * oscale;
                if (BF16OUT)
                    ((unsigned short*)Cp)[(size_t)rowg * 1024 + colg] = f2bf(v);
                else
                    ((float*)Cp)[(size_t)rowg * 1024 + colg] = v;
            }
        }
}

#define QSCALE 0.1803368801111137f   // (1/sqrt(64)) * log2(e)

__global__ __launch_bounds__(256) void k_gemm_qk(const unsigned short* __restrict__ Hb,
                                                 const unsigned short* __restrict__ Wqb,
                                                 const unsigned short* __restrict__ Wkb,
                                                 const float* __restrict__ bq,
                                                 const float* __restrict__ bk,
                                                 unsigned short* __restrict__ Q,
                                                 unsigned short* __restrict__ K) {
    const unsigned short* Bt = blockIdx.z ? Wkb : Wqb;
    const float* bias = blockIdx.z ? bk : bq;
    unsigned short* C = blockIdx.z ? K : Q;
    float os = blockIdx.z ? 1.0f : QSCALE;   // fold softmax scale*log2e into Q
    gemm_body<128, true>(Hb, Bt, bias, C, os);
}

__global__ __launch_bounds__(256) void k_gemm_out(const unsigned short* __restrict__ Ctx,
                                                  const unsigned short* __restrict__ Wob,
                                                  const float* __restrict__ bo,
                                                  float* __restrict__ Out) {
    gemm_body<64, false>(Ctx, Wob, bo, Out, 1.0f);
}

// ---------------- flash attention: barrier-free k-loop, direct global->VGPR K/V ----------
// grid (S/128, NH, B), 256 threads, wave w owns 32 q-rows (2 subtiles). No __syncthreads
// in the k-loop: K/V fragments load straight from global (L1/L2 serve the 4-wave reuse),
// P round-trips through per-wave LDS (same-wave DS ordering). K register-double-buffered.
// K loaded with kpos = 4r+nt permutation so P writes pack as bf16x4.
__global__ __launch_bounds__(256) void k_attn(const unsigned short* __restrict__ Q,
                                              const unsigned short* __restrict__ K,
                                              const unsigned short* __restrict__ Vt,
                                              unsigned short* __restrict__ Ctx) {
    __shared__ unsigned short lsP[4 * 2048];     // per-wave [q32][k64]
    const int tid = threadIdx.x;
    const int lane = tid & 63;
    const int w = tid >> 6;
    const int r = lane & 15, quad = lane >> 4;
    const int qb = blockIdx.x, h = blockIdx.y, b = blockIdx.z;

    // Q A-fragments: A[m=lane&15][k=quad*8+j (+32t)]
    bf16x8 aq[2][2];
#pragma unroll
    for (int sub = 0; sub < 2; ++sub) {
        const int qrow = qb * 128 + w * 32 + sub * 16 + r;
        const size_t qoff = (size_t)(b * SS + qrow) * DD + h * HD;
        aq[sub][0] = *(const bf16x8*)(Q + qoff + quad * 8);
        aq[sub][1] = *(const bf16x8*)(Q + qoff + 32 + quad * 8);
    }

    f32x4 accO[2][4];
#pragma unroll
    for (int sub = 0; sub < 2; ++sub)
#pragma unroll
        for (int nt = 0; nt < 4; ++nt) accO[sub][nt] = f32x4{0.f, 0.f, 0.f, 0.f};
    float lsum[2][4] = {{0.f, 0.f, 0.f, 0.f}, {0.f, 0.f, 0.f, 0.f}};

    // direct-load fragment bases (uniform base + 32-bit per-lane offset)
    const unsigned short* Kb_ = K + (size_t)b * SS * DD + h * HD;          // + kpos*DD + dchunk
    const unsigned short* Vb_ = Vt + (size_t)(b * NH + h) * HD * SS;       // + d*SS + kposchunk
    uint kOff[2][4], vOff[2][4];
#pragma unroll
    for (int t = 0; t < 2; ++t)
#pragma unroll
        for (int nt = 0; nt < 4; ++nt) {
            kOff[t][nt] = (uint)((4 * r + nt) * DD + t * 32 + quad * 8);   // kpos=4r+nt (sigma)
            vOff[t][nt] = (uint)((nt * 16 + r) * SS + t * 32 + quad * 8);  // d=nt*16+r, kpos natural
        }
    // P write/read offsets (row stride 64 ushorts, 16B-chunk xor-swizzle by row&7)
    uint pw[4], pr[2];
#pragma unroll
    for (int reg = 0; reg < 4; ++reg) {
        int prow = quad * 4 + reg;
        pw[reg] = (uint)(prow * 64 + ((r >> 1) ^ (prow & 7)) * 8 + (r & 1) * 4);
    }
#pragma unroll
    for (int t = 0; t < 2; ++t)
        pr[t] = (uint)(r * 64 + ((4 * t + quad) ^ (r & 7)) * 8);
    unsigned short* Pw = lsP + w * 2048;

    // K register double-buffer: preload tile 0
    bf16x8 kf[2][2][4];
#pragma unroll
    for (int t = 0; t < 2; ++t)
#pragma unroll
        for (int nt = 0; nt < 4; ++nt)
            kf[0][t][nt] = *(const bf16x8*)(Kb_ + kOff[t][nt]);

#pragma unroll 2
    for (int kt = 0; kt < 32; ++kt) {
        const int cur = kt & 1;
        const uint kbase_n = (uint)(((kt + 1) & 31) * 64) * DD;   // next K tile (wraps, harmless)
        const uint vbase   = (uint)(kt * 64);

        // V fragments for this tile (consumed after softmax — latency hidden)
        bf16x8 vf[2][4];
#pragma unroll
        for (int t = 0; t < 2; ++t)
#pragma unroll
            for (int nt = 0; nt < 4; ++nt)
                vf[t][nt] = *(const bf16x8*)(Vb_ + vbase + vOff[t][nt]);
        // prefetch next K tile into the other register buffer
#pragma unroll
        for (int t = 0; t < 2; ++t)
#pragma unroll
            for (int nt = 0; nt < 4; ++nt)
                kf[cur ^ 1][t][nt] = *(const bf16x8*)(Kb_ + kbase_n + kOff[t][nt]);

        // S = Q K^T, both subtiles share each K fragment
        f32x4 s[2][4];
#pragma unroll
        for (int sub = 0; sub < 2; ++sub)
#pragma unroll
            for (int nt = 0; nt < 4; ++nt) s[sub][nt] = f32x4{0.f, 0.f, 0.f, 0.f};
#pragma unroll
        for (int t = 0; t < 2; ++t)
#pragma unroll
            for (int nt = 0; nt < 4; ++nt) {
                bf16x8 bk = kf[cur][t][nt];
                s[0][nt] = mfma16(aq[0][t], bk, s[0][nt]);
                s[1][nt] = mfma16(aq[1][t], bk, s[1][nt]);
            }

        // p = exp2(s); packed P write: q-row sub*16+quad*4+reg, k' = 4r + nt
#pragma unroll
        for (int sub = 0; sub < 2; ++sub)
#pragma unroll
            for (int reg = 0; reg < 4; ++reg) {
                float p0 = __builtin_amdgcn_exp2f(s[sub][0][reg]);
                float p1 = __builtin_amdgcn_exp2f(s[sub][1][reg]);
                float p2 = __builtin_amdgcn_exp2f(s[sub][2][reg]);
                float p3 = __builtin_amdgcn_exp2f(s[sub][3][reg]);
                lsum[sub][reg] += (p0 + p1) + (p2 + p3);
                bf16x4 pk = {(__bf16)p0, (__bf16)p1, (__bf16)p2, (__bf16)p3};
                *(bf16x4*)&Pw[sub * 1024 + pw[reg]] = pk;
            }
        // no barrier: P is per-wave, same-wave DS ops are ordered

        // O += P V, both subtiles share each V fragment
#pragma unroll
        for (int t = 0; t < 2; ++t) {
            bf16x8 ap0 = *(const bf16x8*)&Pw[pr[t]];
            bf16x8 ap1 = *(const bf16x8*)&Pw[1024 + pr[t]];
#pragma unroll
            for (int nt = 0; nt < 4; ++nt) {
                bf16x8 bv = vf[t][nt];
                accO[0][nt] = mfma16(ap0, bv, accO[0][nt]);
                accO[1][nt] = mfma16(ap1, bv, accO[1][nt]);
            }
        }
    }

    // epilogue: reduce l across the 16 row-lanes, then O/l -> Ctx bf16
#pragma unroll
    for (int sub = 0; sub < 2; ++sub) {
        float linv[4];
#pragma unroll
        for (int reg = 0; reg < 4; ++reg) {
            float l = lsum[sub][reg];
            l += __shfl_xor(l, 1);
            l += __shfl_xor(l, 2);
            l += __shfl_xor(l, 4);
            l += __shfl_xor(l, 8);
            linv[reg] = 1.0f / l;
        }
#pragma unroll
        for (int nt = 0; nt < 4; ++nt) {
            int d = nt * 16 + r;
#pragma unroll
            for (int reg = 0; reg < 4; ++reg) {
                int qr = qb * 128 + w * 32 + sub * 16 + quad * 4 + reg;
                Ctx[(size_t)(b * SS + qr) * DD + h * HD + d] = f2bf(accO[sub][nt][reg] * linv[reg]);
            }
        }
    }
}

extern "C" void kernel_launch(void* const* d_in, const int* in_sizes, int n_in,
                              void* d_out, int out_size, void* d_ws, size_t ws_size,
                              hipStream_t stream) {
    (void)in_sizes; (void)n_in; (void)out_size; (void)ws_size;
    const float* H  = (const float*)d_in[0];
    const float* Wq = (const float*)d_in[1];
    const float* bq = (const float*)d_in[2];
    const float* Wk = (const float*)d_in[3];
    const float* bk = (const float*)d_in[4];
    const float* Wo = (const float*)d_in[5];
    const float* bo = (const float*)d_in[6];
    float* Out = (float*)d_out;

    char* ws = (char*)d_ws;
    unsigned short* Hb  = (unsigned short*)(ws);                 // 8 MB
    unsigned short* Qb  = (unsigned short*)(ws + 8388608);       // 8 MB (pre-scaled)
    unsigned short* Kb  = (unsigned short*)(ws + 16777216);      // 8 MB
    unsigned short* Ctx = (unsigned short*)(ws + 25165824);      // 8 MB
    unsigned short* Vt  = (unsigned short*)(ws + 33554432);      // 8 MB
    unsigned short* Wqb = (unsigned short*)(ws + 41943040);      // 2 MB
    unsigned short* Wkb = (unsigned short*)(ws + 44040192);      // 2 MB
    unsigned short* Wob = (unsigned short*)(ws + 46137344);      // 2 MB

    k_prep<<<dim3(2048), dim3(256), 0, stream>>>(H, Wq, Wk, Wo, Hb, Vt, Wqb, Wkb, Wob);
    k_gemm_qk<<<dim3(8, 32, 2), dim3(256), 0, stream>>>(Hb, Wqb, Wkb, bq, bk, Qb, Kb);
    k_attn<<<dim3(16, NH, BB), dim3(256), 0, stream>>>(Qb, Kb, Vt, Ctx);
    k_gemm_out<<<dim3(8, 64, 1), dim3(256), 0, stream>>>(Ctx, Wob, bo, Out);
}

// Round 6
// 175.064 us; speedup vs baseline: 1.4001x; 1.4001x over previous
//
#include <hip/hip_runtime.h>
#include <stdint.h>

// Problem dims (fixed)
#define BB 2
#define SS 2048
#define DD 1024
#define NH 16
#define HD 64
#define MM 4096   // BB*SS

typedef __bf16 bf16x8 __attribute__((ext_vector_type(8)));
typedef __bf16 bf16x4 __attribute__((ext_vector_type(4)));
typedef float  f32x4  __attribute__((ext_vector_type(4)));

__device__ __forceinline__ unsigned short f2bf(float f) {
    __bf16 h = (__bf16)f;                       // hw v_cvt, RNE
    return __builtin_bit_cast(unsigned short, h);
}

// async global->LDS, 16B per lane. LDS dst must be wave-uniform base + lane*16.
// NOTE (R5 lesson): this is also the coalescing transform — global side must be
// lane-contiguous. Direct global->VGPR fragment loads (2KB lane stride) ran 2.3x
// slower (127us vs 56us) from transaction explosion despite zero barriers.
__device__ __forceinline__ void async_cp16(const void* g, const void* l) {
    __builtin_amdgcn_global_load_lds(
        (const __attribute__((address_space(1))) void*)(uintptr_t)g,
        (__attribute__((address_space(3))) void*)(uint32_t)(uintptr_t)l,
        16, 0, 0);
}

__device__ __forceinline__ f32x4 mfma16(bf16x8 a, bf16x8 b, f32x4 c) {
    return __builtin_amdgcn_mfma_f32_16x16x32_bf16(a, b, c, 0, 0, 0);
}

// ---------------- fused prep: H->Hb+Vt (blocks 0..511) and W->bf16 (blocks 512..2047) ----
__global__ __launch_bounds__(256) void k_prep(const float* __restrict__ H,
                                              const float* __restrict__ Wq,
                                              const float* __restrict__ Wk,
                                              const float* __restrict__ Wo,
                                              unsigned short* __restrict__ Hb,
                                              unsigned short* __restrict__ Vt,
                                              unsigned short* __restrict__ Wqb,
                                              unsigned short* __restrict__ Wkb,
                                              unsigned short* __restrict__ Wob) {
    __shared__ float tile[128][68];
    const int bx = blockIdx.x;
    const int t = threadIdx.x;
    if (bx >= 512) {  // weight conversion
        int g = bx - 512;
        const float* src; unsigned short* dst; int base;
        if (g < 512)       { src = Wq; dst = Wqb; base = g; }
        else if (g < 1024) { src = Wk; dst = Wkb; base = g - 512; }
        else               { src = Wo; dst = Wob; base = g - 1024; }
        int i = (base * 256 + t) * 8;
        float4 a = *(const float4*)(src + i);
        float4 b = *(const float4*)(src + i + 4);
        unsigned short o[8];
        o[0] = f2bf(a.x); o[1] = f2bf(a.y); o[2] = f2bf(a.z); o[3] = f2bf(a.w);
        o[4] = f2bf(b.x); o[5] = f2bf(b.y); o[6] = f2bf(b.z); o[7] = f2bf(b.w);
        *(ulonglong2*)(dst + i) = *(ulonglong2*)o;
        return;
    }
    const int sb = bx & 15, h = (bx >> 4) & 15, b = bx >> 8;
    const int col4 = t & 15;
    const int srow0 = t >> 4;
#pragma unroll
    for (int p = 0; p < 8; ++p) {
        int s = p * 16 + srow0;
        float4 v = *(const float4*)(H + (size_t)(b * SS + sb * 128 + s) * DD + h * HD + col4 * 4);
        *(float4*)&tile[s][col4 * 4] = v;
    }
    __syncthreads();
#pragma unroll
    for (int it = 0; it < 4; ++it) {
        int task = it * 256 + t;
        int s = task >> 3;
        int dg = task & 7;
        unsigned short pk[8];
#pragma unroll
        for (int j = 0; j < 8; ++j) pk[j] = f2bf(tile[s][dg * 8 + j]);
        *(ulonglong2*)(Hb + (size_t)(b * SS + sb * 128 + s) * DD + h * HD + dg * 8) = *(ulonglong2*)pk;
    }
#pragma unroll
    for (int it = 0; it < 4; ++it) {
        int task = it * 256 + t;
        int d = task >> 4;
        int sg = task & 15;
        unsigned short pk[8];
#pragma unroll
        for (int j = 0; j < 8; ++j) pk[j] = f2bf(tile[sg * 8 + j][d]);
        *(ulonglong2*)(Vt + (size_t)((b * NH + h) * HD + d) * SS + sb * 128 + sg * 8) = *(ulonglong2*)pk;
    }
}

// ---------------- TM x 128 MFMA GEMM, BK=64, double-buffered, 1 barrier/iter ----------------
// C[m][n] = (sum_k A[m][k]*Bt[n][k] + bias[n]) * oscale.  A:[*,1024], Bt:[1024,1024] bf16.
template <int TM, bool BF16OUT>
__device__ __forceinline__ void gemm_body(const unsigned short* __restrict__ A,
                                          const unsigned short* __restrict__ Bt,
                                          const float* __restrict__ bias,
                                          void* __restrict__ Cp, float oscale) {
    constexpr int MT = TM / 32;            // m-frags per wave (waves are 2x2)
    constexpr int AR = TM / 32;            // A staging rounds: TM*8 chunks / 256 lanes
    __shared__ unsigned short lsA[2][TM * 64];
    __shared__ unsigned short lsB[2][128 * 64];
    const int tid = threadIdx.x;
    const int lane = tid & 63;
    const int w = tid >> 6;
    const int wm = w & 1, wn = w >> 1;
    const int r = lane & 15, quad = lane >> 4;
    const int mBase = blockIdx.y * TM;
    const int nBase = blockIdx.x * 128;

    const unsigned short* gA[AR]; uint laOff[AR];
#pragma unroll
    for (int t = 0; t < AR; ++t) {
        int l = t * 256 + tid;
        int c = l ^ ((l >> 3) & 7);
        int row = c >> 3, kc = c & 7;
        gA[t] = A + (size_t)(mBase + row) * 1024 + kc * 8;
        laOff[t] = l * 8;
    }
    const unsigned short* gB[4]; uint lbOff[4];
#pragma unroll
    for (int t = 0; t < 4; ++t) {
        int l = t * 256 + tid;
        int c = l ^ ((l >> 3) & 7);
        int row = c >> 3, kc = c & 7;
        gB[t] = Bt + (size_t)(nBase + row) * 1024 + kc * 8;
        lbOff[t] = l * 8;
    }
    uint aOff[2][MT], bOff[2][4];
#pragma unroll
    for (int hh = 0; hh < 2; ++hh) {
#pragma unroll
        for (int mt = 0; mt < MT; ++mt) {
            int rowA = wm * (TM / 2) + mt * 16 + r;
            int c = rowA * 8 + hh * 4 + quad;
            aOff[hh][mt] = (uint)((c ^ ((c >> 3) & 7)) * 8);
        }
#pragma unroll
        for (int nt = 0; nt < 4; ++nt) {
            int rowB = wn * 64 + nt * 16 + r;
            int c = rowB * 8 + hh * 4 + quad;
            bOff[hh][nt] = (uint)((c ^ ((c >> 3) & 7)) * 8);
        }
    }

    f32x4 acc[MT][4];
#pragma unroll
    for (int i = 0; i < MT; ++i)
#pragma unroll
        for (int j = 0; j < 4; ++j) acc[i][j] = f32x4{0.f, 0.f, 0.f, 0.f};

    auto stage = [&](int buf) {
#pragma unroll
        for (int t = 0; t < AR; ++t) { async_cp16(gA[t], &lsA[buf][laOff[t]]); gA[t] += 64; }
#pragma unroll
        for (int t = 0; t < 4; ++t)  { async_cp16(gB[t], &lsB[buf][lbOff[t]]); gB[t] += 64; }
    };

    stage(0);
    for (int kb = 0; kb < 16; ++kb) {
        const int cur = kb & 1;
        __syncthreads();   // drains vmcnt: buf[cur] ready, prev reads of buf[cur^1] done
        if (kb + 1 < 16) stage(cur ^ 1);

#pragma unroll
        for (int hh = 0; hh < 2; ++hh) {
            bf16x8 af[MT], bf[4];
#pragma unroll
            for (int mt = 0; mt < MT; ++mt) af[mt] = *(const bf16x8*)&lsA[cur][aOff[hh][mt]];
#pragma unroll
            for (int nt = 0; nt < 4; ++nt)  bf[nt] = *(const bf16x8*)&lsB[cur][bOff[hh][nt]];
#pragma unroll
            for (int mt = 0; mt < MT; ++mt)
#pragma unroll
                for (int nt = 0; nt < 4; ++nt)
                    acc[mt][nt] = mfma16(af[mt], bf[nt], acc[mt][nt]);
        }
    }

    float bv[4];
#pragma unroll
    for (int nt = 0; nt < 4; ++nt) bv[nt] = bias[nBase + wn * 64 + nt * 16 + r];
#pragma unroll
    for (int mt = 0; mt < MT; ++mt)
#pragma unroll
        for (int nt = 0; nt < 4; ++nt) {
            int colg = nBase + wn * 64 + nt * 16 + r;
#pragma unroll
            for (int reg = 0; reg < 4; ++reg) {
                int rowg = mBase + wm * (TM / 2) + mt * 16 + quad * 4 + reg;
                float v = (acc[mt][nt][reg] + bv[nt]) * oscale;
                if (BF16OUT)
                    ((unsigned short*)Cp)[(size_t)rowg * 1024 + colg] = f2bf(v);
                else
                    ((float*)Cp)[(size_t)rowg * 1024 + colg] = v;
            }
        }
}

#define QSCALE 0.1803368801111137f   // (1/sqrt(64)) * log2(e)

__global__ __launch_bounds__(256) void k_gemm_qk(const unsigned short* __restrict__ Hb,
                                                 const unsigned short* __restrict__ Wqb,
                                                 const unsigned short* __restrict__ Wkb,
                                                 const float* __restrict__ bq,
                                                 const float* __restrict__ bk,
                                                 unsigned short* __restrict__ Q,
                                                 unsigned short* __restrict__ K) {
    const unsigned short* Bt = blockIdx.z ? Wkb : Wqb;
    const float* bias = blockIdx.z ? bk : bq;
    unsigned short* C = blockIdx.z ? K : Q;
    float os = blockIdx.z ? 1.0f : QSCALE;   // fold softmax scale*log2e into Q
    gemm_body<128, true>(Hb, Bt, bias, C, os);
}

__global__ __launch_bounds__(256) void k_gemm_out(const unsigned short* __restrict__ Ctx,
                                                  const unsigned short* __restrict__ Wob,
                                                  const float* __restrict__ bo,
                                                  float* __restrict__ Out) {
    gemm_body<64, false>(Ctx, Wob, bo, Out, 1.0f);
}

// ---------------- flash attention: 2-wave blocks, LDS-staged K/V, 1 barrier/iter ----------
// grid (S/64, NH, B), 128 threads. Each wave owns 32 q-rows (2 subtiles sharing K/V frags).
// 40 KB LDS -> 4 blocks/CU; barrier couples only 2 waves, 4 independent blocks/CU hide
// each other's vmcnt drains. Q pre-scaled by scale*log2e so p = exp2(s); per-lane l-sum.
__global__ __launch_bounds__(128) void k_attn(const unsigned short* __restrict__ Q,
                                              const unsigned short* __restrict__ K,
                                              const unsigned short* __restrict__ Vt,
                                              unsigned short* __restrict__ Ctx) {
    __shared__ unsigned short lsK[2][64 * 64];   // [buf][row][d], rows sigma-permuted
    __shared__ unsigned short lsV[2][64 * 64];   // [buf][d][kpos] natural
    __shared__ unsigned short lsP[2 * 2048];     // per-wave [q32][k64]
    const int tid = threadIdx.x;
    const int lane = tid & 63;
    const int w = tid >> 6;
    const int r = lane & 15, quad = lane >> 4;
    const int qb = blockIdx.x, h = blockIdx.y, b = blockIdx.z;

    // Q A-fragments for both subtiles: A[m=lane&15][k=quad*8+j (+32t)]
    bf16x8 aq[2][2];
#pragma unroll
    for (int sub = 0; sub < 2; ++sub) {
        const int qrow = qb * 64 + w * 32 + sub * 16 + r;
        const size_t qoff = (size_t)(b * SS + qrow) * DD + h * HD;
        aq[sub][0] = *(const bf16x8*)(Q + qoff + quad * 8);
        aq[sub][1] = *(const bf16x8*)(Q + qoff + 32 + quad * 8);
    }

    f32x4 accO[2][4];
#pragma unroll
    for (int sub = 0; sub < 2; ++sub)
#pragma unroll
        for (int nt = 0; nt < 4; ++nt) accO[sub][nt] = f32x4{0.f, 0.f, 0.f, 0.f};
    float lsum[2][4] = {{0.f, 0.f, 0.f, 0.f}, {0.f, 0.f, 0.f, 0.f}};

    // hoisted staging addresses (4 rounds each for K and V with 128 threads)
    const unsigned short* gK[4]; const unsigned short* gV[4]; uint lO[4];
#pragma unroll
    for (int t = 0; t < 4; ++t) {
        int l = t * 128 + tid;
        int c = l ^ ((l >> 3) & 7);
        int row = c >> 3, kc = c & 7;
        int srow = 4 * (row & 15) + (row >> 4);   // sigma: S col nt*16+r <-> kpos 4r+nt
        gK[t] = K + (size_t)(b * SS + srow) * DD + h * HD + kc * 8;
        gV[t] = Vt + (size_t)((b * NH + h) * HD + row) * SS + kc * 8;
        lO[t] = l * 8;
    }
    // LDS frag offsets (ushort units) — same formula serves lsK and lsV
    uint off[2][4];
#pragma unroll
    for (int t = 0; t < 2; ++t)
#pragma unroll
        for (int nt = 0; nt < 4; ++nt) {
            int rowX = nt * 16 + r;
            int c = rowX * 8 + t * 4 + quad;
            off[t][nt] = (uint)((c ^ ((c >> 3) & 7)) * 8);
        }
    // P write/read offsets (row stride 64 ushorts, 16B-chunk xor-swizzle by row&7)
    uint pw[4], pr[2];
#pragma unroll
    for (int reg = 0; reg < 4; ++reg) {
        int prow = quad * 4 + reg;
        pw[reg] = (uint)(prow * 64 + ((r >> 1) ^ (prow & 7)) * 8 + (r & 1) * 4);
    }
#pragma unroll
    for (int t = 0; t < 2; ++t)
        pr[t] = (uint)(r * 64 + ((4 * t + quad) ^ (r & 7)) * 8);
    unsigned short* Pw = lsP + w * 2048;

    auto stage = [&](int buf) {
#pragma unroll
        for (int t = 0; t < 4; ++t) {
            async_cp16(gK[t], &lsK[buf][lO[t]]); gK[t] += 64 * DD;
            async_cp16(gV[t], &lsV[buf][lO[t]]); gV[t] += 64;
        }
    };

    stage(0);
    for (int kt = 0; kt < 32; ++kt) {
        const int cur = kt & 1;
        __syncthreads();
        if (kt + 1 < 32) stage(cur ^ 1);

        // S = Q K^T, both subtiles share each K fragment
        f32x4 s[2][4];
#pragma unroll
        for (int sub = 0; sub < 2; ++sub)
#pragma unroll
            for (int nt = 0; nt < 4; ++nt) s[sub][nt] = f32x4{0.f, 0.f, 0.f, 0.f};
#pragma unroll
        for (int t = 0; t < 2; ++t)
#pragma unroll
            for (int nt = 0; nt < 4; ++nt) {
                bf16x8 bk = *(const bf16x8*)&lsK[cur][off[t][nt]];
                s[0][nt] = mfma16(aq[0][t], bk, s[0][nt]);
                s[1][nt] = mfma16(aq[1][t], bk, s[1][nt]);
            }

        // p = exp2(s); packed P write: q-row sub*16+quad*4+reg, k' = 4r + nt
#pragma unroll
        for (int sub = 0; sub < 2; ++sub)
#pragma unroll
            for (int reg = 0; reg < 4; ++reg) {
                float p0 = __builtin_amdgcn_exp2f(s[sub][0][reg]);
                float p1 = __builtin_amdgcn_exp2f(s[sub][1][reg]);
                float p2 = __builtin_amdgcn_exp2f(s[sub][2][reg]);
                float p3 = __builtin_amdgcn_exp2f(s[sub][3][reg]);
                lsum[sub][reg] += (p0 + p1) + (p2 + p3);
                bf16x4 pk = {(__bf16)p0, (__bf16)p1, (__bf16)p2, (__bf16)p3};
                *(bf16x4*)&Pw[sub * 1024 + pw[reg]] = pk;
            }
        // no barrier: P is per-wave, same-wave DS ops are ordered

        // O += P V, both subtiles share each V fragment
#pragma unroll
        for (int t = 0; t < 2; ++t) {
            bf16x8 ap0 = *(const bf16x8*)&Pw[pr[t]];
            bf16x8 ap1 = *(const bf16x8*)&Pw[1024 + pr[t]];
#pragma unroll
            for (int nt = 0; nt < 4; ++nt) {
                bf16x8 bv = *(const bf16x8*)&lsV[cur][off[t][nt]];
                accO[0][nt] = mfma16(ap0, bv, accO[0][nt]);
                accO[1][nt] = mfma16(ap1, bv, accO[1][nt]);
            }
        }
    }

    // epilogue: reduce l across the 16 row-lanes, then O/l -> Ctx bf16
#pragma unroll
    for (int sub = 0; sub < 2; ++sub) {
        float linv[4];
#pragma unroll
        for (int reg = 0; reg < 4; ++reg) {
            float l = lsum[sub][reg];
            l += __shfl_xor(l, 1);
            l += __shfl_xor(l, 2);
            l += __shfl_xor(l, 4);
            l += __shfl_xor(l, 8);
            linv[reg] = 1.0f / l;
        }
#pragma unroll
        for (int nt = 0; nt < 4; ++nt) {
            int d = nt * 16 + r;
#pragma unroll
            for (int reg = 0; reg < 4; ++reg) {
                int qr = qb * 64 + w * 32 + sub * 16 + quad * 4 + reg;
                Ctx[(size_t)(b * SS + qr) * DD + h * HD + d] = f2bf(accO[sub][nt][reg] * linv[reg]);
            }
        }
    }
}

extern "C" void kernel_launch(void* const* d_in, const int* in_sizes, int n_in,
                              void* d_out, int out_size, void* d_ws, size_t ws_size,
                              hipStream_t stream) {
    (void)in_sizes; (void)n_in; (void)out_size; (void)ws_size;
    const float* H  = (const float*)d_in[0];
    const float* Wq = (const float*)d_in[1];
    const float* bq = (const float*)d_in[2];
    const float* Wk = (const float*)d_in[3];
    const float* bk = (const float*)d_in[4];
    const float* Wo = (const float*)d_in[5];
    const float* bo = (const float*)d_in[6];
    float* Out = (float*)d_out;

    char* ws = (char*)d_ws;
    unsigned short* Hb  = (unsigned short*)(ws);                 // 8 MB
    unsigned short* Qb  = (unsigned short*)(ws + 8388608);       // 8 MB (pre-scaled)
    unsigned short* Kb  = (unsigned short*)(ws + 16777216);      // 8 MB
    unsigned short* Ctx = (unsigned short*)(ws + 25165824);      // 8 MB
    unsigned short* Vt  = (unsigned short*)(ws + 33554432);      // 8 MB
    unsigned short* Wqb = (unsigned short*)(ws + 41943040);      // 2 MB
    unsigned short* Wkb = (unsigned short*)(ws + 44040192);      // 2 MB
    unsigned short* Wob = (unsigned short*)(ws + 46137344);      // 2 MB

    k_prep<<<dim3(2048), dim3(256), 0, stream>>>(H, Wq, Wk, Wo, Hb, Vt, Wqb, Wkb, Wob);
    k_gemm_qk<<<dim3(8, 32, 2), dim3(256), 0, stream>>>(Hb, Wqb, Wkb, bq, bk, Qb, Kb);
    k_attn<<<dim3(32, NH, BB), dim3(128), 0, stream>>>(Qb, Kb, Vt, Ctx);
    k_gemm_out<<<dim3(8, 64, 1), dim3(256), 0, stream>>>(Ctx, Wob, bo, Out);
}